// Round 13
// baseline (318.606 us; speedup 1.0000x reference)
//
#include <hip/hip_runtime.h>
#include <cmath>

namespace {
constexpr int NB  = 256;   // batch
constexpr int CI  = 64;    // in channels
constexpr int CO  = 64;    // out channels
constexpr int TT  = 64;    // time
constexpr int V   = 25;    // vertices
constexpr int REL = 8;     // rel channels
constexpr int TV  = TT * V;   // 1600
constexpr int CC  = 8;     // channels per fused block
constexpr int TH  = 32;    // t per block (t-split across grid)
constexpr int IP  = 28;    // inp row pad (16B-aligned rows)
constexpr int AP  = 28;    // Af row pad (16B-aligned rows)
}

typedef float f4 __attribute__((ext_vector_type(4)));

__device__ __forceinline__ float fast_tanh(float x) {
  float ax = fabsf(x);
  float e  = __expf(-2.f * ax);          // v_exp based
  float r  = (1.f - e) / (1.f + e);
  return copysignf(r, x);
}

// ---------------------------------------------------------------------------
// K1: per-n temporal reduction -> x1,x2 (REL*V each) into ws. (unchanged)
// ---------------------------------------------------------------------------
__global__ __launch_bounds__(1024) void k1_x12(
    const float* __restrict__ x,
    const float* __restrict__ w1, const float* __restrict__ b1,
    const float* __restrict__ w2, const float* __restrict__ b2,
    float* __restrict__ ws) {
  const int n = blockIdx.x;
  const int tid = threadIdx.x;
  __shared__ __align__(16) float xs[8][TV];
  __shared__ float xsum[CI][V];
  __shared__ float w12[2][REL][CI];

  for (int idx = tid; idx < 2 * REL * CI; idx += 1024) {
    int half = idx / (REL * CI), rem = idx % (REL * CI);
    w12[half][rem / CI][rem % CI] = half ? w2[rem] : w1[rem];
  }

  const float4* xb = reinterpret_cast<const float4*>(x + (size_t)n * (CI * TV));
  float4* xsv = reinterpret_cast<float4*>(&xs[0][0]);
  constexpr int V4G = 8 * TV / 4;  // 3200

  for (int g = 0; g < 8; ++g) {
    __syncthreads();
    for (int idx = tid; idx < V4G; idx += 1024)
      xsv[idx] = xb[g * V4G + idx];
    __syncthreads();
    if (tid < 8 * V) {
      int ch = tid / V, v = tid % V;
      float acc = 0.f;
      #pragma unroll
      for (int t = 0; t < TT; ++t) acc += xs[ch][t * V + v];
      xsum[g * 8 + ch][v] = acc;
    }
  }
  __syncthreads();

  if (tid < 2 * REL * V) {
    int half = tid / (REL * V), rem = tid % (REL * V);
    int r = rem / V, v = rem % V;
    float a = 0.f;
    #pragma unroll
    for (int i = 0; i < CI; ++i) a = fmaf(w12[half][r][i], xsum[i][v], a);
    ws[(size_t)n * (2 * REL * V) + tid] = a * (1.f / TT) + (half ? b2[r] : b1[r]);
  }
}

// ---------------------------------------------------------------------------
// K2 fused, t-split grid: block = (n, cb, th). 4096 blocks.
//   id = [n_hi5][cb3][th1][n_lo3]: id%8 == n%8 (XCD-local), all 16 blocks of
//   an n dispatch-adjacent -> x[n] HBM-fetched once per XCD.
//   P0: zero inp pads; Af[8][25][28] (fast_tanh inline, pad cols 0)
//   P1: inp[8][32][28] for this block's t-range (400 float2-columns)
//   P2: 256 thr, acc[4][7] (proven R7/R11 density: 77 LDS reads / 784 FMA),
//       t-rows tq+8*ti, u-rows 6*uq..6*uq+6 (overlaps benign).
// LDS 51072 B -> 3 blocks/CU; __launch_bounds__(512,6) caps VGPR at 85
// (R11 measured 64 for identical P2 -> no spill expected).
// ---------------------------------------------------------------------------
__global__ __launch_bounds__(512, 6) void k2_fused(
    const float* __restrict__ x, const float* __restrict__ A,
    const float* __restrict__ w3, const float* __restrict__ b3,
    const float* __restrict__ wr, const float* __restrict__ br,
    const float* __restrict__ ws, float* __restrict__ out) {
  const int id  = blockIdx.x;
  const int n   = (id & 7) | ((id >> 7) << 3);
  const int th  = (id >> 3) & 1;
  const int cb  = (id >> 4) & 7;
  const int c0  = cb * CC;
  const int tid = threadIdx.x;       // 0..511

  __shared__ __align__(16) float inp[CC * TH * IP];   // 28672 B
  __shared__ __align__(16) float Afs[CC * V * AP];    // 22400 B

  // ---- P0a: zero inp pad columns (v=25..27) for all 256 rows
  if (tid < CC * TH) {
    float* row = inp + tid * IP;
    row[25] = 0.f; row[26] = 0.f; row[27] = 0.f;
  }

  // ---- P0b: Af[cc][u][v] = A[u][v]+b3[c]+sum_r w3[c][r]*tanh(x1[r][u]-x2[r][v])
  //           pad columns (v>=25) = 0 (so f4 chunk 6 is safe)
  const float* x1n = ws + (size_t)n * (2 * REL * V);
  const float* x2n = x1n + REL * V;
  for (int idx = tid; idx < V * AP; idx += 512) {      // 700 tasks
    int u = idx / AP, v = idx % AP;
    if (v < V) {
      float t8[REL];
      #pragma unroll
      for (int r = 0; r < REL; ++r)
        t8[r] = fast_tanh(x1n[r * V + u] - x2n[r * V + v]);
      const float base = A[u * V + v];
      #pragma unroll
      for (int cc = 0; cc < CC; ++cc) {
        float acc = base + b3[c0 + cc];                // uniform -> s_load
        #pragma unroll
        for (int r = 0; r < REL; ++r)
          acc = fmaf(w3[(c0 + cc) * REL + r], t8[r], acc);  // uniform -> s_load
        Afs[(cc * V + u) * AP + v] = acc;
      }
    } else {
      #pragma unroll
      for (int cc = 0; cc < CC; ++cc)
        Afs[(cc * V + u) * AP + v] = 0.f;
    }
  }
  __syncthreads();

  // ---- P1: inp[cc][tloc][v] for this th's 32 t's. 400 float2-columns.
  //          weights via uniform global reads -> s_load.
  if (tid < TH * V / 2) {                              // 400 threads
    const float* xp = x + (size_t)n * (CI * TV) + th * (TH * V) + tid * 2;
    float acc[CC][2];
    #pragma unroll
    for (int cc = 0; cc < CC; ++cc) {
      float b = br[c0 + cc];                           // uniform -> s_load
      acc[cc][0] = b; acc[cc][1] = b;
    }
    #pragma unroll 8
    for (int i = 0; i < CI; ++i) {
      float2 xv = *reinterpret_cast<const float2*>(xp + (size_t)i * TV);
      float w8[CC];
      #pragma unroll
      for (int cc = 0; cc < CC; ++cc)
        w8[cc] = wr[(size_t)(c0 + cc) * CI + i];       // uniform -> s_load
      #pragma unroll
      for (int cc = 0; cc < CC; ++cc) {
        acc[cc][0] = fmaf(w8[cc], xv.x, acc[cc][0]);
        acc[cc][1] = fmaf(w8[cc], xv.y, acc[cc][1]);
      }
    }
    int tv0 = tid * 2;
    int t = tv0 / V, v = tv0 % V;
    #pragma unroll
    for (int k = 0; k < 2; ++k) {
      #pragma unroll
      for (int cc = 0; cc < CC; ++cc)
        inp[(cc * TH + t) * IP + v] = acc[cc][k];
      if (++v == V) { v = 0; ++t; }
    }
  }
  __syncthreads();

  // ---- P2 (tid < 256): thread = (cc, tq, uq). t-rows {tq+8*ti, ti=0..3};
  //      u-rows {6*uq .. 6*uq+6}. Per chk: 4 inp f4 + 7 Af f4, 112 FMA.
  if (tid < 256) {
    const int cc = tid >> 5;          // 0..7
    const int tq = (tid >> 2) & 7;    // 0..7
    const int uq = tid & 3;           // 0..3
    const int u0 = uq * 6;

    float acc[4][7];
    #pragma unroll
    for (int a = 0; a < 4; ++a)
      #pragma unroll
      for (int b = 0; b < 7; ++b) acc[a][b] = 0.f;

    const float* ib = &inp[(cc * TH + tq) * IP];
    const float* ab = &Afs[(cc * V + u0) * AP];

    #pragma unroll
    for (int chk = 0; chk < 7; ++chk) {
      const f4 x0 = *reinterpret_cast<const f4*>(ib + 0 * 8 * IP + chk * 4);
      const f4 x1 = *reinterpret_cast<const f4*>(ib + 1 * 8 * IP + chk * 4);
      const f4 x2 = *reinterpret_cast<const f4*>(ib + 2 * 8 * IP + chk * 4);
      const f4 x3 = *reinterpret_cast<const f4*>(ib + 3 * 8 * IP + chk * 4);
      #pragma unroll
      for (int ku = 0; ku < 7; ++ku) {
        const f4 a = *reinterpret_cast<const f4*>(ab + ku * AP + chk * 4);
        acc[0][ku] = fmaf(a.w, x0.w, fmaf(a.z, x0.z, fmaf(a.y, x0.y, fmaf(a.x, x0.x, acc[0][ku]))));
        acc[1][ku] = fmaf(a.w, x1.w, fmaf(a.z, x1.z, fmaf(a.y, x1.y, fmaf(a.x, x1.x, acc[1][ku]))));
        acc[2][ku] = fmaf(a.w, x2.w, fmaf(a.z, x2.z, fmaf(a.y, x2.y, fmaf(a.x, x2.x, acc[2][ku]))));
        acc[3][ku] = fmaf(a.w, x3.w, fmaf(a.z, x3.z, fmaf(a.y, x3.y, fmaf(a.x, x3.x, acc[3][ku]))));
      }
    }

    float* ob = out + (((size_t)n * CO + (c0 + cc)) * TT + th * TH) * V;
    #pragma unroll
    for (int ti = 0; ti < 4; ++ti) {
      const int t = tq + 8 * ti;
      #pragma unroll
      for (int ku = 0; ku < 7; ++ku)
        ob[t * V + u0 + ku] = acc[ti][ku];
    }
  }
}

extern "C" void kernel_launch(void* const* d_in, const int* in_sizes, int n_in,
                              void* d_out, int out_size, void* d_ws, size_t ws_size,
                              hipStream_t stream) {
  (void)in_sizes; (void)n_in; (void)out_size; (void)ws_size;
  const float* x  = (const float*)d_in[0];
  const float* A  = (const float*)d_in[1];
  const float* w1 = (const float*)d_in[2];
  const float* b1 = (const float*)d_in[3];
  const float* w2 = (const float*)d_in[4];
  const float* b2 = (const float*)d_in[5];
  const float* w3 = (const float*)d_in[6];
  const float* b3 = (const float*)d_in[7];
  const float* wr = (const float*)d_in[8];
  const float* br = (const float*)d_in[9];
  float* out = (float*)d_out;
  float* ws  = (float*)d_ws;

  hipLaunchKernelGGL(k1_x12, dim3(NB), dim3(1024), 0, stream,
                     x, w1, b1, w2, b2, ws);
  hipLaunchKernelGGL(k2_fused, dim3(NB * CO / CC * 2), dim3(512), 0, stream,
                     x, A, w3, b3, wr, br, ws, out);
}

// Round 14
// 153.911 us; speedup vs baseline: 2.0701x; 2.0701x over previous
//
#include <hip/hip_runtime.h>
#include <cmath>

namespace {
constexpr int NB  = 256;   // batch
constexpr int CI  = 64;    // in channels
constexpr int CO  = 64;    // out channels
constexpr int TT  = 64;    // time
constexpr int V   = 25;    // vertices
constexpr int REL = 8;     // rel channels
constexpr int TV  = TT * V;   // 1600
constexpr int CC  = 8;     // channels per fused block
constexpr int TH  = 32;    // t per block (t-split across grid)
constexpr int IP  = 28;    // inp row pad (16B-aligned rows)
constexpr int AP  = 28;    // Af row pad (16B-aligned rows)
}

typedef float f4 __attribute__((ext_vector_type(4)));

__device__ __forceinline__ float fast_tanh(float x) {
  float ax = fabsf(x);
  float e  = __expf(-2.f * ax);          // v_exp based
  float r  = (1.f - e) / (1.f + e);
  return copysignf(r, x);
}

// ---------------------------------------------------------------------------
// K1: per-n temporal reduction -> x1,x2 (REL*V each) into ws. (unchanged)
// ---------------------------------------------------------------------------
__global__ __launch_bounds__(1024) void k1_x12(
    const float* __restrict__ x,
    const float* __restrict__ w1, const float* __restrict__ b1,
    const float* __restrict__ w2, const float* __restrict__ b2,
    float* __restrict__ ws) {
  const int n = blockIdx.x;
  const int tid = threadIdx.x;
  __shared__ __align__(16) float xs[8][TV];
  __shared__ float xsum[CI][V];
  __shared__ float w12[2][REL][CI];

  for (int idx = tid; idx < 2 * REL * CI; idx += 1024) {
    int half = idx / (REL * CI), rem = idx % (REL * CI);
    w12[half][rem / CI][rem % CI] = half ? w2[rem] : w1[rem];
  }

  const float4* xb = reinterpret_cast<const float4*>(x + (size_t)n * (CI * TV));
  float4* xsv = reinterpret_cast<float4*>(&xs[0][0]);
  constexpr int V4G = 8 * TV / 4;  // 3200

  for (int g = 0; g < 8; ++g) {
    __syncthreads();
    for (int idx = tid; idx < V4G; idx += 1024)
      xsv[idx] = xb[g * V4G + idx];
    __syncthreads();
    if (tid < 8 * V) {
      int ch = tid / V, v = tid % V;
      float acc = 0.f;
      #pragma unroll
      for (int t = 0; t < TT; ++t) acc += xs[ch][t * V + v];
      xsum[g * 8 + ch][v] = acc;
    }
  }
  __syncthreads();

  if (tid < 2 * REL * V) {
    int half = tid / (REL * V), rem = tid % (REL * V);
    int r = rem / V, v = rem % V;
    float a = 0.f;
    #pragma unroll
    for (int i = 0; i < CI; ++i) a = fmaf(w12[half][r][i], xsum[i][v], a);
    ws[(size_t)n * (2 * REL * V) + tid] = a * (1.f / TT) + (half ? b2[r] : b1[r]);
  }
}

// ---------------------------------------------------------------------------
// K2 fused, t-split grid (R13 structure), NO __launch_bounds__:
//   empirical law on this kernel family: (512,6)->VGPR 40 (spill, R9/R10/R13),
//   (512,4)->64 (R11/R12); unconstrained -> 68-72 (R2/R4), which fits P2's
//   ~60-reg working set AND the 3-blocks/CU wave budget (6 waves/SIMD needs
//   VGPR<=85).
//   id = [n_hi5][cb3][th1][n_lo3]: id%8 == n%8 (XCD-local), all 16 blocks of
//   an n dispatch-adjacent -> x[n] served from L3/L2 (R9: FETCH 57 MB).
//   P0: zero inp pads; Af[8][25][28] (fast_tanh inline, pad cols 0)
//   P1: inp[8][32][28] for this block's t-range (400 float2-columns)
//   P2: 256 thr, acc[4][7] (optimal 11 LDS reads / 112 FMA), t-rows tq+8*ti.
// LDS 51072 B -> 3 blocks/CU.
// ---------------------------------------------------------------------------
__global__ void k2_fused(
    const float* __restrict__ x, const float* __restrict__ A,
    const float* __restrict__ w3, const float* __restrict__ b3,
    const float* __restrict__ wr, const float* __restrict__ br,
    const float* __restrict__ ws, float* __restrict__ out) {
  const int id  = blockIdx.x;
  const int n   = (id & 7) | ((id >> 7) << 3);
  const int th  = (id >> 3) & 1;
  const int cb  = (id >> 4) & 7;
  const int c0  = cb * CC;
  const int tid = threadIdx.x;       // 0..511

  __shared__ __align__(16) float inp[CC * TH * IP];   // 28672 B
  __shared__ __align__(16) float Afs[CC * V * AP];    // 22400 B

  // ---- P0a: zero inp pad columns (v=25..27) for all 256 rows
  if (tid < CC * TH) {
    float* row = inp + tid * IP;
    row[25] = 0.f; row[26] = 0.f; row[27] = 0.f;
  }

  // ---- P0b: Af[cc][u][v] = A[u][v]+b3[c]+sum_r w3[c][r]*tanh(x1[r][u]-x2[r][v])
  //           pad columns (v>=25) = 0 (so f4 chunk 6 is safe)
  const float* x1n = ws + (size_t)n * (2 * REL * V);
  const float* x2n = x1n + REL * V;
  for (int idx = tid; idx < V * AP; idx += 512) {      // 700 tasks
    int u = idx / AP, v = idx % AP;
    if (v < V) {
      float t8[REL];
      #pragma unroll
      for (int r = 0; r < REL; ++r)
        t8[r] = fast_tanh(x1n[r * V + u] - x2n[r * V + v]);
      const float base = A[u * V + v];
      #pragma unroll
      for (int cc = 0; cc < CC; ++cc) {
        float acc = base + b3[c0 + cc];                // uniform -> s_load
        #pragma unroll
        for (int r = 0; r < REL; ++r)
          acc = fmaf(w3[(c0 + cc) * REL + r], t8[r], acc);  // uniform -> s_load
        Afs[(cc * V + u) * AP + v] = acc;
      }
    } else {
      #pragma unroll
      for (int cc = 0; cc < CC; ++cc)
        Afs[(cc * V + u) * AP + v] = 0.f;
    }
  }
  __syncthreads();

  // ---- P1: inp[cc][tloc][v] for this th's 32 t's. 400 float2-columns.
  //          weights via uniform global reads -> s_load.
  if (tid < TH * V / 2) {                              // 400 threads
    const float* xp = x + (size_t)n * (CI * TV) + th * (TH * V) + tid * 2;
    float acc[CC][2];
    #pragma unroll
    for (int cc = 0; cc < CC; ++cc) {
      float b = br[c0 + cc];                           // uniform -> s_load
      acc[cc][0] = b; acc[cc][1] = b;
    }
    #pragma unroll 8
    for (int i = 0; i < CI; ++i) {
      float2 xv = *reinterpret_cast<const float2*>(xp + (size_t)i * TV);
      float w8[CC];
      #pragma unroll
      for (int cc = 0; cc < CC; ++cc)
        w8[cc] = wr[(size_t)(c0 + cc) * CI + i];       // uniform -> s_load
      #pragma unroll
      for (int cc = 0; cc < CC; ++cc) {
        acc[cc][0] = fmaf(w8[cc], xv.x, acc[cc][0]);
        acc[cc][1] = fmaf(w8[cc], xv.y, acc[cc][1]);
      }
    }
    int tv0 = tid * 2;
    int t = tv0 / V, v = tv0 % V;
    #pragma unroll
    for (int k = 0; k < 2; ++k) {
      #pragma unroll
      for (int cc = 0; cc < CC; ++cc)
        inp[(cc * TH + t) * IP + v] = acc[cc][k];
      if (++v == V) { v = 0; ++t; }
    }
  }
  __syncthreads();

  // ---- P2 (tid < 256): thread = (cc, tq, uq). t-rows {tq+8*ti, ti=0..3};
  //      u-rows {6*uq .. 6*uq+6}. Per chk: 4 inp f4 + 7 Af f4, 112 FMA.
  //      Idle upper waves' SIMD slots backfill from the other 2 resident
  //      blocks (the point of 3 blocks/CU).
  if (tid < 256) {
    const int cc = tid >> 5;          // 0..7
    const int tq = (tid >> 2) & 7;    // 0..7
    const int uq = tid & 3;           // 0..3
    const int u0 = uq * 6;

    float acc[4][7];
    #pragma unroll
    for (int a = 0; a < 4; ++a)
      #pragma unroll
      for (int b = 0; b < 7; ++b) acc[a][b] = 0.f;

    const float* ib = &inp[(cc * TH + tq) * IP];
    const float* ab = &Afs[(cc * V + u0) * AP];

    #pragma unroll
    for (int chk = 0; chk < 7; ++chk) {
      const f4 x0 = *reinterpret_cast<const f4*>(ib + 0 * 8 * IP + chk * 4);
      const f4 x1 = *reinterpret_cast<const f4*>(ib + 1 * 8 * IP + chk * 4);
      const f4 x2 = *reinterpret_cast<const f4*>(ib + 2 * 8 * IP + chk * 4);
      const f4 x3 = *reinterpret_cast<const f4*>(ib + 3 * 8 * IP + chk * 4);
      #pragma unroll
      for (int ku = 0; ku < 7; ++ku) {
        const f4 a = *reinterpret_cast<const f4*>(ab + ku * AP + chk * 4);
        acc[0][ku] = fmaf(a.w, x0.w, fmaf(a.z, x0.z, fmaf(a.y, x0.y, fmaf(a.x, x0.x, acc[0][ku]))));
        acc[1][ku] = fmaf(a.w, x1.w, fmaf(a.z, x1.z, fmaf(a.y, x1.y, fmaf(a.x, x1.x, acc[1][ku]))));
        acc[2][ku] = fmaf(a.w, x2.w, fmaf(a.z, x2.z, fmaf(a.y, x2.y, fmaf(a.x, x2.x, acc[2][ku]))));
        acc[3][ku] = fmaf(a.w, x3.w, fmaf(a.z, x3.z, fmaf(a.y, x3.y, fmaf(a.x, x3.x, acc[3][ku]))));
      }
    }

    float* ob = out + (((size_t)n * CO + (c0 + cc)) * TT + th * TH) * V;
    #pragma unroll
    for (int ti = 0; ti < 4; ++ti) {
      const int t = tq + 8 * ti;
      #pragma unroll
      for (int ku = 0; ku < 7; ++ku)
        ob[t * V + u0 + ku] = acc[ti][ku];
    }
  }
}

extern "C" void kernel_launch(void* const* d_in, const int* in_sizes, int n_in,
                              void* d_out, int out_size, void* d_ws, size_t ws_size,
                              hipStream_t stream) {
  (void)in_sizes; (void)n_in; (void)out_size; (void)ws_size;
  const float* x  = (const float*)d_in[0];
  const float* A  = (const float*)d_in[1];
  const float* w1 = (const float*)d_in[2];
  const float* b1 = (const float*)d_in[3];
  const float* w2 = (const float*)d_in[4];
  const float* b2 = (const float*)d_in[5];
  const float* w3 = (const float*)d_in[6];
  const float* b3 = (const float*)d_in[7];
  const float* wr = (const float*)d_in[8];
  const float* br = (const float*)d_in[9];
  float* out = (float*)d_out;
  float* ws  = (float*)d_ws;

  hipLaunchKernelGGL(k1_x12, dim3(NB), dim3(1024), 0, stream,
                     x, w1, b1, w2, b2, ws);
  hipLaunchKernelGGL(k2_fused, dim3(NB * CO / CC * 2), dim3(512), 0, stream,
                     x, A, w3, b3, wr, br, ws, out);
}

// Round 15
// 143.298 us; speedup vs baseline: 2.2234x; 1.0741x over previous
//
#include <hip/hip_runtime.h>
#include <cmath>

namespace {
constexpr int NB  = 256;   // batch
constexpr int CI  = 64;    // in channels
constexpr int CO  = 64;    // out channels
constexpr int TT  = 64;    // time
constexpr int V   = 25;    // vertices
constexpr int REL = 8;     // rel channels
constexpr int TV  = TT * V;   // 1600
constexpr int CC  = 8;     // channels per fused block
constexpr int IP  = 28;    // inp row pad (16B-aligned rows)
constexpr int AP  = 28;    // Af row pad (16B-aligned rows)
}

typedef float f4 __attribute__((ext_vector_type(4)));

__device__ __forceinline__ float fast_tanh(float x) {
  float ax = fabsf(x);
  float e  = __expf(-2.f * ax);          // v_exp based
  float r  = (1.f - e) / (1.f + e);
  return copysignf(r, x);
}

// ---------------------------------------------------------------------------
// K1: per-n temporal reduction -> x1,x2 (REL*V each) into ws. (unchanged)
// ---------------------------------------------------------------------------
__global__ __launch_bounds__(1024) void k1_x12(
    const float* __restrict__ x,
    const float* __restrict__ w1, const float* __restrict__ b1,
    const float* __restrict__ w2, const float* __restrict__ b2,
    float* __restrict__ ws) {
  const int n = blockIdx.x;
  const int tid = threadIdx.x;
  __shared__ __align__(16) float xs[8][TV];
  __shared__ float xsum[CI][V];
  __shared__ float w12[2][REL][CI];

  for (int idx = tid; idx < 2 * REL * CI; idx += 1024) {
    int half = idx / (REL * CI), rem = idx % (REL * CI);
    w12[half][rem / CI][rem % CI] = half ? w2[rem] : w1[rem];
  }

  const float4* xb = reinterpret_cast<const float4*>(x + (size_t)n * (CI * TV));
  float4* xsv = reinterpret_cast<float4*>(&xs[0][0]);
  constexpr int V4G = 8 * TV / 4;  // 3200

  for (int g = 0; g < 8; ++g) {
    __syncthreads();
    for (int idx = tid; idx < V4G; idx += 1024)
      xsv[idx] = xb[g * V4G + idx];
    __syncthreads();
    if (tid < 8 * V) {
      int ch = tid / V, v = tid % V;
      float acc = 0.f;
      #pragma unroll
      for (int t = 0; t < TT; ++t) acc += xs[ch][t * V + v];
      xsum[g * 8 + ch][v] = acc;
    }
  }
  __syncthreads();

  if (tid < 2 * REL * V) {
    int half = tid / (REL * V), rem = tid % (REL * V);
    int r = rem / V, v = rem % V;
    float a = 0.f;
    #pragma unroll
    for (int i = 0; i < CI; ++i) a = fmaf(w12[half][r][i], xsum[i][v], a);
    ws[(size_t)n * (2 * REL * V) + tid] = a * (1.f / TT) + (half ? b2[r] : b1[r]);
  }
}

// ---------------------------------------------------------------------------
// K2 fused == R11 (best: k2 139.5us, VGPR 64, no spill) plus:
//   - fast_tanh (v_exp) in P0b            [validated R12-R14, absmax 0.125]
//   - P1 #pragma unroll 8                 [validated R12]
//   - minimal pad zeroing in P0a          [validated R12-R14]
//   - NON-TEMPORAL out stores in P2: out lines are write-once/never-read ->
//     keep them out of L2 (kills dirty-line churn = WRITE 249MB, and stops
//     out from evicting x = FETCH 113MB vs R9's 57MB).
//   grid swizzle id=[n_hi5][cb3][n_lo3] -> 8 cb-blocks of an n on one XCD.
// LDS 79744 B -> 2 blocks/CU. wr/br/w3/b3 via wave-uniform s_loads.
// ---------------------------------------------------------------------------
__global__ __launch_bounds__(512, 4) void k2_fused(
    const float* __restrict__ x, const float* __restrict__ A,
    const float* __restrict__ w3, const float* __restrict__ b3,
    const float* __restrict__ wr, const float* __restrict__ br,
    const float* __restrict__ ws, float* __restrict__ out) {
  const int id  = blockIdx.x;
  const int n   = (id & 7) | ((id >> 3) & ~7);
  const int cb  = (id >> 3) & 7;
  const int c0  = cb * CC;
  const int tid = threadIdx.x;       // 0..511

  __shared__ __align__(16) float inp[CC * TT * IP];   // 57344 B
  __shared__ __align__(16) float Afs[CC * V * AP];    // 22400 B

  // ---- P0a: zero inp pad columns (v=25..27) for all 512 rows (tid == row)
  {
    float* row = inp + tid * IP;
    row[25] = 0.f; row[26] = 0.f; row[27] = 0.f;
  }

  // ---- P0b: Af[cc][u][v] = A[u][v]+b3[c]+sum_r w3[c][r]*tanh(x1[r][u]-x2[r][v])
  //           pad columns (v>=25) = 0 (so f4 chunk 6 is safe)
  const float* x1n = ws + (size_t)n * (2 * REL * V);
  const float* x2n = x1n + REL * V;
  for (int idx = tid; idx < V * AP; idx += 512) {      // 700 tasks
    int u = idx / AP, v = idx % AP;
    if (v < V) {
      float t8[REL];
      #pragma unroll
      for (int r = 0; r < REL; ++r)
        t8[r] = fast_tanh(x1n[r * V + u] - x2n[r * V + v]);
      const float base = A[u * V + v];
      #pragma unroll
      for (int cc = 0; cc < CC; ++cc) {
        float acc = base + b3[c0 + cc];                // uniform -> s_load
        #pragma unroll
        for (int r = 0; r < REL; ++r)
          acc = fmaf(w3[(c0 + cc) * REL + r], t8[r], acc);  // uniform -> s_load
        Afs[(cc * V + u) * AP + v] = acc;
      }
    } else {
      #pragma unroll
      for (int cc = 0; cc < CC; ++cc)
        Afs[(cc * V + u) * AP + v] = 0.f;
    }
  }
  __syncthreads();

  // ---- P1: inputs tile (all t) into LDS. 400 threads own float4 tv-columns.
  //          weights via uniform global reads -> s_load.
  if (tid < TV / 4) {
    const float* xp = x + (size_t)n * (CI * TV) + tid * 4;
    float acc[CC][4];
    #pragma unroll
    for (int cc = 0; cc < CC; ++cc) {
      float b = br[c0 + cc];                           // uniform -> s_load
      acc[cc][0] = b; acc[cc][1] = b; acc[cc][2] = b; acc[cc][3] = b;
    }
    #pragma unroll 8
    for (int i = 0; i < CI; ++i) {
      float4 xv = *reinterpret_cast<const float4*>(xp + (size_t)i * TV);
      float w8[CC];
      #pragma unroll
      for (int cc = 0; cc < CC; ++cc)
        w8[cc] = wr[(size_t)(c0 + cc) * CI + i];       // uniform -> s_load
      #pragma unroll
      for (int cc = 0; cc < CC; ++cc) {
        acc[cc][0] = fmaf(w8[cc], xv.x, acc[cc][0]);
        acc[cc][1] = fmaf(w8[cc], xv.y, acc[cc][1]);
        acc[cc][2] = fmaf(w8[cc], xv.z, acc[cc][2]);
        acc[cc][3] = fmaf(w8[cc], xv.w, acc[cc][3]);
      }
    }
    int tv0 = tid * 4;
    int t = tv0 / V, v = tv0 % V;
    #pragma unroll
    for (int k = 0; k < 4; ++k) {
      #pragma unroll
      for (int cc = 0; cc < CC; ++cc)
        inp[(cc * TT + t) * IP + v] = acc[cc][k];
      if (++v == V) { v = 0; ++t; }
    }
  }
  __syncthreads();

  // ---- P2: thread = (cc, tq, uq). t-rows {tq, tq+16, tq+32, tq+48};
  //      u-rows {6*uq .. 6*uq+6} (overlap at 6/12/18 -> benign dup stores).
  //      acc[4][7] in regs; per v-chunk: 4 inp f4 + 7 Af f4, consumed at once.
  const int cc = tid >> 6;            // 0..7
  const int tq = (tid >> 2) & 15;     // 0..15
  const int uq = tid & 3;             // 0..3
  const int u0 = uq * 6;

  float acc[4][7];
  #pragma unroll
  for (int a = 0; a < 4; ++a)
    #pragma unroll
    for (int b = 0; b < 7; ++b) acc[a][b] = 0.f;

  const float* ib = &inp[(cc * TT + tq) * IP];
  const float* ab = &Afs[(cc * V + u0) * AP];

  #pragma unroll
  for (int chk = 0; chk < 7; ++chk) {
    const f4 x0 = *reinterpret_cast<const f4*>(ib + 0 * 16 * IP + chk * 4);
    const f4 x1 = *reinterpret_cast<const f4*>(ib + 1 * 16 * IP + chk * 4);
    const f4 x2 = *reinterpret_cast<const f4*>(ib + 2 * 16 * IP + chk * 4);
    const f4 x3 = *reinterpret_cast<const f4*>(ib + 3 * 16 * IP + chk * 4);
    #pragma unroll
    for (int ku = 0; ku < 7; ++ku) {
      const f4 a = *reinterpret_cast<const f4*>(ab + ku * AP + chk * 4);
      acc[0][ku] = fmaf(a.w, x0.w, fmaf(a.z, x0.z, fmaf(a.y, x0.y, fmaf(a.x, x0.x, acc[0][ku]))));
      acc[1][ku] = fmaf(a.w, x1.w, fmaf(a.z, x1.z, fmaf(a.y, x1.y, fmaf(a.x, x1.x, acc[1][ku]))));
      acc[2][ku] = fmaf(a.w, x2.w, fmaf(a.z, x2.z, fmaf(a.y, x2.y, fmaf(a.x, x2.x, acc[2][ku]))));
      acc[3][ku] = fmaf(a.w, x3.w, fmaf(a.z, x3.z, fmaf(a.y, x3.y, fmaf(a.x, x3.x, acc[3][ku]))));
    }
  }

  float* ob = out + ((size_t)n * CO + (c0 + cc)) * (size_t)(TT * V);
  #pragma unroll
  for (int ti = 0; ti < 4; ++ti) {
    const int t = tq + 16 * ti;
    #pragma unroll
    for (int ku = 0; ku < 7; ++ku)
      __builtin_nontemporal_store(acc[ti][ku], &ob[t * V + u0 + ku]);
  }
}

extern "C" void kernel_launch(void* const* d_in, const int* in_sizes, int n_in,
                              void* d_out, int out_size, void* d_ws, size_t ws_size,
                              hipStream_t stream) {
  (void)in_sizes; (void)n_in; (void)out_size; (void)ws_size;
  const float* x  = (const float*)d_in[0];
  const float* A  = (const float*)d_in[1];
  const float* w1 = (const float*)d_in[2];
  const float* b1 = (const float*)d_in[3];
  const float* w2 = (const float*)d_in[4];
  const float* b2 = (const float*)d_in[5];
  const float* w3 = (const float*)d_in[6];
  const float* b3 = (const float*)d_in[7];
  const float* wr = (const float*)d_in[8];
  const float* br = (const float*)d_in[9];
  float* out = (float*)d_out;
  float* ws  = (float*)d_ws;

  hipLaunchKernelGGL(k1_x12, dim3(NB), dim3(1024), 0, stream,
                     x, w1, b1, w2, b2, ws);
  hipLaunchKernelGGL(k2_fused, dim3(NB * CO / CC), dim3(512), 0, stream,
                     x, A, w3, b3, wr, br, ws, out);
}

// Round 16
// 138.359 us; speedup vs baseline: 2.3027x; 1.0357x over previous
//
#include <hip/hip_runtime.h>
#include <cmath>

namespace {
constexpr int NB  = 256;   // batch
constexpr int CI  = 64;    // in channels
constexpr int CO  = 64;    // out channels
constexpr int TT  = 64;    // time
constexpr int V   = 25;    // vertices
constexpr int REL = 8;     // rel channels
constexpr int TV  = TT * V;   // 1600
constexpr int CC  = 8;     // channels per block (Af scope)
constexpr int CH  = 4;     // channels per inp-staging half
constexpr int IP  = 28;    // inp row pad (16B-aligned rows)
constexpr int AP  = 28;    // Af row pad (16B-aligned rows)
}

typedef float f4 __attribute__((ext_vector_type(4)));

__device__ __forceinline__ float fast_tanh(float x) {
  float ax = fabsf(x);
  float e  = __expf(-2.f * ax);          // v_exp based
  float r  = (1.f - e) / (1.f + e);
  return copysignf(r, x);
}

// ---------------------------------------------------------------------------
// K1: per-n temporal reduction -> x1,x2 (REL*V each) into ws. (unchanged)
// ---------------------------------------------------------------------------
__global__ __launch_bounds__(1024) void k1_x12(
    const float* __restrict__ x,
    const float* __restrict__ w1, const float* __restrict__ b1,
    const float* __restrict__ w2, const float* __restrict__ b2,
    float* __restrict__ ws) {
  const int n = blockIdx.x;
  const int tid = threadIdx.x;
  __shared__ __align__(16) float xs[8][TV];
  __shared__ float xsum[CI][V];
  __shared__ float w12[2][REL][CI];

  for (int idx = tid; idx < 2 * REL * CI; idx += 1024) {
    int half = idx / (REL * CI), rem = idx % (REL * CI);
    w12[half][rem / CI][rem % CI] = half ? w2[rem] : w1[rem];
  }

  const float4* xb = reinterpret_cast<const float4*>(x + (size_t)n * (CI * TV));
  float4* xsv = reinterpret_cast<float4*>(&xs[0][0]);
  constexpr int V4G = 8 * TV / 4;  // 3200

  for (int g = 0; g < 8; ++g) {
    __syncthreads();
    for (int idx = tid; idx < V4G; idx += 1024)
      xsv[idx] = xb[g * V4G + idx];
    __syncthreads();
    if (tid < 8 * V) {
      int ch = tid / V, v = tid % V;
      float acc = 0.f;
      #pragma unroll
      for (int t = 0; t < TT; ++t) acc += xs[ch][t * V + v];
      xsum[g * 8 + ch][v] = acc;
    }
  }
  __syncthreads();

  if (tid < 2 * REL * V) {
    int half = tid / (REL * V), rem = tid % (REL * V);
    int r = rem / V, v = rem % V;
    float a = 0.f;
    #pragma unroll
    for (int i = 0; i < CI; ++i) a = fmaf(w12[half][r][i], xsum[i][v], a);
    ws[(size_t)n * (2 * REL * V) + tid] = a * (1.f / TT) + (half ? b2[r] : b1[r]);
  }
}

// ---------------------------------------------------------------------------
// K2 fused, cc-halved staging for 3 blocks/CU:
//   LDS = inp[4][64][28] (28672 B) + Afs[8][25][28] (22400 B) = 51072 B
//   -> 3 blocks/CU (R15 was 79744 -> 2). Af built ONCE per block.
//   loop ch=0,1: P1 stages 4 channels' inputs (400 thr, float4 columns,
//                acc[4][4]); P2 consumes (256 thr, acc[4][7] -- the proven
//                11 LDS reads / 112 FMA density; t-rows tq+16*ti).
//   Plain stores (NOT non-temporal): R9 evidence -- at 3 blk/CU the L2 merges
//   the wave's full-line coverage, WRITE ~1.1x logical.
//   grid swizzle id=[n_hi5][cb3][n_lo3] -> 8 cb-blocks of an n on one XCD.
//   fast_tanh + P1 unroll 8 + minimal pad-zero kept from R15.
// ---------------------------------------------------------------------------
__global__ __launch_bounds__(512, 4) void k2_fused(
    const float* __restrict__ x, const float* __restrict__ A,
    const float* __restrict__ w3, const float* __restrict__ b3,
    const float* __restrict__ wr, const float* __restrict__ br,
    const float* __restrict__ ws, float* __restrict__ out) {
  const int id  = blockIdx.x;
  const int n   = (id & 7) | ((id >> 3) & ~7);
  const int cb  = (id >> 3) & 7;
  const int c0  = cb * CC;
  const int tid = threadIdx.x;       // 0..511

  __shared__ __align__(16) float inp[CH * TT * IP];   // 28672 B
  __shared__ __align__(16) float Afs[CC * V * AP];    // 22400 B

  // ---- P0a: zero inp pad columns (v=25..27) for all 256 rows
  if (tid < CH * TT) {
    float* row = inp + tid * IP;
    row[25] = 0.f; row[26] = 0.f; row[27] = 0.f;
  }

  // ---- P0b: Af[cc][u][v] = A[u][v]+b3[c]+sum_r w3[c][r]*tanh(x1[r][u]-x2[r][v])
  //           pad columns (v>=25) = 0 (so f4 chunk 6 is safe)
  const float* x1n = ws + (size_t)n * (2 * REL * V);
  const float* x2n = x1n + REL * V;
  for (int idx = tid; idx < V * AP; idx += 512) {      // 700 tasks
    int u = idx / AP, v = idx % AP;
    if (v < V) {
      float t8[REL];
      #pragma unroll
      for (int r = 0; r < REL; ++r)
        t8[r] = fast_tanh(x1n[r * V + u] - x2n[r * V + v]);
      const float base = A[u * V + v];
      #pragma unroll
      for (int cc = 0; cc < CC; ++cc) {
        float acc = base + b3[c0 + cc];                // uniform -> s_load
        #pragma unroll
        for (int r = 0; r < REL; ++r)
          acc = fmaf(w3[(c0 + cc) * REL + r], t8[r], acc);  // uniform -> s_load
        Afs[(cc * V + u) * AP + v] = acc;
      }
    } else {
      #pragma unroll
      for (int cc = 0; cc < CC; ++cc)
        Afs[(cc * V + u) * AP + v] = 0.f;
    }
  }
  __syncthreads();

  for (int ch = 0; ch < 2; ++ch) {
    const int cbase = c0 + ch * CH;

    // ---- P1: inputs tile (all t, 4 channels) into LDS. 400 float4-columns.
    //          weights via uniform global reads -> s_load.
    if (tid < TV / 4) {
      const float* xp = x + (size_t)n * (CI * TV) + tid * 4;
      float acc[CH][4];
      #pragma unroll
      for (int cc = 0; cc < CH; ++cc) {
        float b = br[cbase + cc];                      // uniform -> s_load
        acc[cc][0] = b; acc[cc][1] = b; acc[cc][2] = b; acc[cc][3] = b;
      }
      #pragma unroll 8
      for (int i = 0; i < CI; ++i) {
        float4 xv = *reinterpret_cast<const float4*>(xp + (size_t)i * TV);
        float w4[CH];
        #pragma unroll
        for (int cc = 0; cc < CH; ++cc)
          w4[cc] = wr[(size_t)(cbase + cc) * CI + i];  // uniform -> s_load
        #pragma unroll
        for (int cc = 0; cc < CH; ++cc) {
          acc[cc][0] = fmaf(w4[cc], xv.x, acc[cc][0]);
          acc[cc][1] = fmaf(w4[cc], xv.y, acc[cc][1]);
          acc[cc][2] = fmaf(w4[cc], xv.z, acc[cc][2]);
          acc[cc][3] = fmaf(w4[cc], xv.w, acc[cc][3]);
        }
      }
      int tv0 = tid * 4;
      int t = tv0 / V, v = tv0 % V;
      #pragma unroll
      for (int k = 0; k < 4; ++k) {
        #pragma unroll
        for (int cc = 0; cc < CH; ++cc)
          inp[(cc * TT + t) * IP + v] = acc[cc][k];
        if (++v == V) { v = 0; ++t; }
      }
    }
    __syncthreads();

    // ---- P2 (tid < 256): thread = (ccl, tq, uq). t-rows {tq+16*ti};
    //      u-rows {6*uq .. 6*uq+6} (overlaps benign). acc[4][7];
    //      per v-chunk: 4 inp f4 + 7 Af f4, consumed immediately.
    if (tid < 256) {
      const int ccl = tid >> 6;         // 0..3
      const int tq  = (tid >> 2) & 15;  // 0..15
      const int uq  = tid & 3;          // 0..3
      const int u0  = uq * 6;

      float acc[4][7];
      #pragma unroll
      for (int a = 0; a < 4; ++a)
        #pragma unroll
        for (int b = 0; b < 7; ++b) acc[a][b] = 0.f;

      const float* ib = &inp[(ccl * TT + tq) * IP];
      const float* ab = &Afs[((ch * CH + ccl) * V + u0) * AP];

      #pragma unroll
      for (int chk = 0; chk < 7; ++chk) {
        const f4 x0 = *reinterpret_cast<const f4*>(ib + 0 * 16 * IP + chk * 4);
        const f4 x1 = *reinterpret_cast<const f4*>(ib + 1 * 16 * IP + chk * 4);
        const f4 x2 = *reinterpret_cast<const f4*>(ib + 2 * 16 * IP + chk * 4);
        const f4 x3 = *reinterpret_cast<const f4*>(ib + 3 * 16 * IP + chk * 4);
        #pragma unroll
        for (int ku = 0; ku < 7; ++ku) {
          const f4 a = *reinterpret_cast<const f4*>(ab + ku * AP + chk * 4);
          acc[0][ku] = fmaf(a.w, x0.w, fmaf(a.z, x0.z, fmaf(a.y, x0.y, fmaf(a.x, x0.x, acc[0][ku]))));
          acc[1][ku] = fmaf(a.w, x1.w, fmaf(a.z, x1.z, fmaf(a.y, x1.y, fmaf(a.x, x1.x, acc[1][ku]))));
          acc[2][ku] = fmaf(a.w, x2.w, fmaf(a.z, x2.z, fmaf(a.y, x2.y, fmaf(a.x, x2.x, acc[2][ku]))));
          acc[3][ku] = fmaf(a.w, x3.w, fmaf(a.z, x3.z, fmaf(a.y, x3.y, fmaf(a.x, x3.x, acc[3][ku]))));
        }
      }

      float* ob = out + ((size_t)n * CO + (cbase + ccl)) * (size_t)(TT * V);
      #pragma unroll
      for (int ti = 0; ti < 4; ++ti) {
        const int t = tq + 16 * ti;
        #pragma unroll
        for (int ku = 0; ku < 7; ++ku)
          ob[t * V + u0 + ku] = acc[ti][ku];
      }
    }
    if (ch == 0) __syncthreads();   // P1(ch=1) overwrites inp
  }
}

extern "C" void kernel_launch(void* const* d_in, const int* in_sizes, int n_in,
                              void* d_out, int out_size, void* d_ws, size_t ws_size,
                              hipStream_t stream) {
  (void)in_sizes; (void)n_in; (void)out_size; (void)ws_size;
  const float* x  = (const float*)d_in[0];
  const float* A  = (const float*)d_in[1];
  const float* w1 = (const float*)d_in[2];
  const float* b1 = (const float*)d_in[3];
  const float* w2 = (const float*)d_in[4];
  const float* b2 = (const float*)d_in[5];
  const float* w3 = (const float*)d_in[6];
  const float* b3 = (const float*)d_in[7];
  const float* wr = (const float*)d_in[8];
  const float* br = (const float*)d_in[9];
  float* out = (float*)d_out;
  float* ws  = (float*)d_ws;

  hipLaunchKernelGGL(k1_x12, dim3(NB), dim3(1024), 0, stream,
                     x, w1, b1, w2, b2, ws);
  hipLaunchKernelGGL(k2_fused, dim3(NB * CO / CC), dim3(512), 0, stream,
                     x, A, w3, b3, wr, br, ws, out);
}